// Round 11
// baseline (190.393 us; speedup 1.0000x reference)
//
#include <hip/hip_runtime.h>
#include <hip/hip_bf16.h>

// LinearPredictionHead: 4-expert last-token linear heads + dense-gate log-sum-exp combine.
// out[b,p,c] = log( sum_e gates[b,e] * exp( dot(xs_e[b,c,-1,:], W_e[:,p]) + b_e[p] ) )
// Round 11: round-6 structure (best) with the reduce fused into the GEMM via the
// split-K "last block combines" pattern: per-(mt,nt) device-scope counter; the
// 4th expert block to finish sums the 4 planes, logs, transposes, stores out.
// Combine math/order identical to reduce_log -> bitwise-deterministic output.
// K-loop is the proven single-__syncthreads 2-phase (R6). 2 dispatches total.

typedef __attribute__((ext_vector_type(4))) float f32x4;
typedef __attribute__((ext_vector_type(8))) short bf16x8;
typedef __attribute__((ext_vector_type(4))) unsigned short u16x4;
typedef __attribute__((ext_vector_type(8))) unsigned short u16x8;

#define EPSV 2.2204460492503131e-16f

__device__ __forceinline__ unsigned short f2bf(float f) {
  unsigned u = __builtin_bit_cast(unsigned, f);
  u += 0x7fffu + ((u >> 16) & 1u);   // round-to-nearest-even
  return (unsigned short)(u >> 16);
}
__device__ __forceinline__ float bf2f(unsigned short h) {
  unsigned u = ((unsigned)h) << 16;
  return __builtin_bit_cast(float, u);
}
__device__ __forceinline__ void gload_lds16(const void* g, void* l) {
  __builtin_amdgcn_global_load_lds(
      (const __attribute__((address_space(1))) unsigned int*)g,
      (__attribute__((address_space(3))) unsigned int*)l, 16, 0, 0);
}

// ---------------- prep (fused): X last tokens -> bf16 [4][2048][1024]
//                  + W [1024][720] -> bf16 W^T [4][720][1024]; zero counters --
__global__ __launch_bounds__(256) void prep_fused(
    const float* __restrict__ xs0, const float* __restrict__ xs1,
    const float* __restrict__ xs2, const float* __restrict__ xs3,
    const float* __restrict__ W0, const float* __restrict__ W1,
    const float* __restrict__ W2, const float* __restrict__ W3,
    unsigned short* __restrict__ Xb, unsigned short* __restrict__ Wb,
    unsigned int* __restrict__ ctr)
{
  __shared__ __align__(16) unsigned short tile[64 * 72];  // W path only
  const int tid = threadIdx.x;
  if (blockIdx.x < 4096) {
    // ---- X path (validated) ----
    const int i = blockIdx.x * 256 + tid;          // 8 elems each
    const int e = i >> 18;
    const int rem = i & 262143;
    const int m = rem >> 7;
    const int kc = rem & 127;
    const float* xp = (e == 0) ? xs0 : (e == 1) ? xs1 : (e == 2) ? xs2 : xs3;
    const int L = 32 >> e;                         // 32,16,8,4
    const float* src = xp + ((size_t)m * L + (L - 1)) * 1024 + kc * 8;
    f32x4 v0 = *(const f32x4*)src;
    f32x4 v1 = *(const f32x4*)(src + 4);
    u16x8 pk;
    pk[0] = f2bf(v0[0]); pk[1] = f2bf(v0[1]); pk[2] = f2bf(v0[2]); pk[3] = f2bf(v0[3]);
    pk[4] = f2bf(v1[0]); pk[5] = f2bf(v1[1]); pk[6] = f2bf(v1[2]); pk[7] = f2bf(v1[3]);
    *(u16x8*)(Xb + ((size_t)e * 2048 + m) * 1024 + kc * 8) = pk;
  } else {
    // ---- W path (validated) ----
    const int wI = blockIdx.x - 4096;              // 0..767 = 16 k x 12 n x 4 e
    if (wI == 0 && tid < 96) ctr[tid] = 0;         // reset tile counters each call
    const int k0 = (wI & 15) * 64;
    const int rest = wI >> 4;
    const int nb = (rest % 12) * 64;
    const int e = rest / 12;
    const float* Wp = (e == 0) ? W0 : (e == 1) ? W1 : (e == 2) ? W2 : W3;
    const int n_c = tid & 15;
    const int r = tid >> 4;
    const int n0 = nb + n_c * 4;
#pragma unroll
    for (int j = 0; j < 4; ++j) {
      const int row = r + j * 16;
      f32x4 v = {0.f, 0.f, 0.f, 0.f};
      if (n0 < 720) v = *(const f32x4*)(Wp + (size_t)(k0 + row) * 720 + n0);
#pragma unroll
      for (int d = 0; d < 4; ++d) tile[(n_c * 4 + d) * 72 + row] = f2bf(v[d]);
    }
    __syncthreads();
    const int n_l = tid >> 2;
    const int kq = tid & 3;
    if (nb + n_l < 720) {
#pragma unroll
      for (int q = 0; q < 2; ++q) {
        const int chunk = q * 4 + kq;
        *(u16x8*)(Wb + ((size_t)e * 720 + nb + n_l) * 1024 + k0 + chunk * 8) =
            *(const u16x8*)(tile + n_l * 72 + chunk * 8);
      }
    }
  }
}

// ---------------- GEMM per expert + fused last-block combine ------------------
// 128x128 tile, 8 waves (2 wm x 4 wn), wave-tile 64x32, BK=64, 16 K-steps,
// dbuf LDS (64KB), single-__syncthreads 2-phase (R6, validated).
// Grid 384 = 6nt*16mt*4e, XCD-chunked bijection. After plane stores, the 4th
// block of each (mt,nt) tile combines: sum 4 planes, log, transpose, store out.
__global__ __launch_bounds__(512) void moe_gemm_e(
    const unsigned short* __restrict__ Xb, const unsigned short* __restrict__ Wb,
    const float* __restrict__ gates,
    const float* __restrict__ b0, const float* __restrict__ b1,
    const float* __restrict__ b2, const float* __restrict__ b3,
    unsigned short* __restrict__ planes,
    unsigned int* __restrict__ ctr, float* __restrict__ out)
{
  __shared__ __align__(16) unsigned char smem[65536];
  __shared__ int is_last;
  unsigned short* a_lds = (unsigned short*)smem;            // [2][128*64] = 32KB
  unsigned short* b_lds = (unsigned short*)(smem + 32768);  // [2][128*64] = 32KB

  const int tid = threadIdx.x;
  const int lane = tid & 63;
  const int wid = tid >> 6;          // 0..7
  const int wm = wid >> 2;           // 0..1 : 64-row half
  const int wn = wid & 3;            // 0..3 : 32-col quarter

  // XCD-chunked bijection: XCD x gets contiguous ids [x*48, (x+1)*48)
  const int id = ((int)blockIdx.x & 7) * 48 + ((int)blockIdx.x >> 3);
  const int nt = id % 6;             // 6 N-tiles of 128 (last ragged: 720-640=80)
  const int mt = (id / 6) % 16;      // 16 M-tiles of 128
  const int e  = id / 96;
  const int nbase = nt * 128;

  const float* barr[4] = {b0, b1, b2, b3};
  // wave rows mt*128 + wm*64 + mf*16: batch = mt*4 + wm*2 + (mf>>1)
  float g_r[2];
#pragma unroll
  for (int h = 0; h < 2; ++h)
    g_r[h] = gates[(mt * 4 + wm * 2 + h) * 4 + e];
  float bias_r[2];
#pragma unroll
  for (int nf = 0; nf < 2; ++nf) {
    int col = nbase + wn * 32 + nf * 16 + (lane & 15);
    bias_r[nf] = barr[e][col < 720 ? col : 719];
  }

  const unsigned short* asrc = Xb + (size_t)e * 2048 * 1024 + (size_t)mt * 128 * 1024;
  const unsigned short* bsrc = Wb + (size_t)e * 720 * 1024;

  // stage: A 128x64 (1024 chunks) + B 128x64 (1024 chunks), 4 loads/thread.
  // LDS dst linear; global src pre-swizzled with the read-side XOR (m173/#21).
  auto stage = [&](int k0, int buf) {
#pragma unroll
    for (int j = 0; j < 2; ++j) {
      const int C = j * 512 + tid;
      const int row = C >> 3, c = C & 7;
      gload_lds16(asrc + (size_t)row * 1024 + k0 + ((c ^ (row & 7)) * 8),
                  a_lds + buf * 8192 + C * 8);
    }
#pragma unroll
    for (int j = 0; j < 2; ++j) {
      const int C = j * 512 + tid;
      const int row = C >> 3, c = C & 7;
      int n = nbase + row; if (n > 719) n = 719;  // clamp; stores guarded later
      gload_lds16(bsrc + (size_t)n * 1024 + k0 + ((c ^ (row & 7)) * 8),
                  b_lds + buf * 8192 + C * 8);
    }
  };

  auto compute = [&](int buf, f32x4 (&acc)[4][2]) {
    const unsigned short* al = a_lds + buf * 8192;
    const unsigned short* bl = b_lds + buf * 8192;
#pragma unroll
    for (int ks = 0; ks < 2; ++ks) {
      const int kb = ks * 64 + (lane >> 4) * 16;  // byte offset within 128B row
      bf16x8 af[4], bfm[2];
#pragma unroll
      for (int mf = 0; mf < 4; ++mf) {
        const int r = wm * 64 + mf * 16 + (lane & 15);
        const int byte = (r * 128 + kb) ^ ((r & 7) << 4);
        af[mf] = *(const bf16x8*)((const char*)al + byte);
      }
#pragma unroll
      for (int nf = 0; nf < 2; ++nf) {
        const int r = wn * 32 + nf * 16 + (lane & 15);
        const int byte = (r * 128 + kb) ^ ((r & 7) << 4);
        bfm[nf] = *(const bf16x8*)((const char*)bl + byte);
      }
#pragma unroll
      for (int mf = 0; mf < 4; ++mf)
#pragma unroll
        for (int nf = 0; nf < 2; ++nf)
          acc[mf][nf] = __builtin_amdgcn_mfma_f32_16x16x32_bf16(
              af[mf], bfm[nf], acc[mf][nf], 0, 0, 0);
    }
  };

  f32x4 acc[4][2] = {};
  int cur = 0;
  stage(0, 0);
  __syncthreads();
  for (int kt = 0; kt < 16; ++kt) {
    if (kt < 15) stage((kt + 1) * 64, cur ^ 1);  // next-tile loads fly during compute
    compute(cur, acc);
    __syncthreads();                             // drain + barrier (proven structure)
    cur ^= 1;
  }

  // epilogue: planes[e][m][p] = bf16(g * exp(acc + bias))
#pragma unroll
  for (int nf = 0; nf < 2; ++nf) {
    const int p = nbase + wn * 32 + nf * 16 + (lane & 15);
    if (p < 720) {
#pragma unroll
      for (int mf = 0; mf < 4; ++mf) {
        const int m0 = mt * 128 + wm * 64 + mf * 16 + ((lane >> 4) << 2);
        const float g = g_r[mf >> 1];
        unsigned short* dst = planes + ((size_t)e * 2048 + m0) * 720 + p;
#pragma unroll
        for (int j = 0; j < 4; ++j)
          dst[j * 720] = f2bf(g * __expf(acc[mf][nf][j] + bias_r[nf]));
      }
    }
  }

  // ---- fused combine: last block of this (mt,nt) tile does reduce+log+store --
  __threadfence();                   // release my plane stores (device scope)
  __syncthreads();                   // all threads' stores fenced
  if (tid == 0) {
    unsigned old = __hip_atomic_fetch_add(&ctr[mt * 6 + nt], 1u,
                                          __ATOMIC_ACQ_REL,
                                          __HIP_MEMORY_SCOPE_AGENT);
    is_last = (old == 3u);
  }
  __syncthreads();
  if (!is_last) return;
  __threadfence();                   // acquire: all threads see remote planes

  float* t = (float*)smem;           // [128][36] f32 transpose buffer (18.4KB)
  for (int bq = 0; bq < 4; ++bq) {
    const int m0 = mt * 128 + bq * 32;
    const int bI = mt * 4 + bq;
    // phase 1: 32 c-rows x 16 p-chunks (u16x8), one per thread
    {
      const int c = tid >> 4;        // 0..31
      const int pc = tid & 15;       // 0..15 -> 128 p
      int p0 = nbase + pc * 8;
      if (p0 > 712) p0 = 712;        // clamp; t rows for p>=720 never read
      const size_t base = ((size_t)m0 + c) * 720 + p0;
      float s[8] = {};
#pragma unroll
      for (int pl = 0; pl < 4; ++pl) {
        u16x8 v = *(const u16x8*)(planes + (size_t)pl * 2048 * 720 + base);
#pragma unroll
        for (int d = 0; d < 8; ++d) s[d] += bf2f(v[d]);
      }
      const int pl0 = p0 - nbase;
#pragma unroll
      for (int d = 0; d < 8; ++d) {
        float v = s[d];
        v = (v == 0.0f) ? EPSV : v;
        t[(pl0 + d) * 36 + c] = __logf(v);
      }
    }
    __syncthreads();
    // phase 2: 128 p x 8 c-chunks (f32x4) = 1024, two per thread
#pragma unroll
    for (int it = 0; it < 2; ++it) {
      const int i = it * 512 + tid;
      const int p_l = i >> 3;
      const int cc = i & 7;
      const int p = nbase + p_l;
      if (p < 720)
        *(f32x4*)(out + ((size_t)bI * 720 + p) * 32 + cc * 4) =
            *(const f32x4*)(t + p_l * 36 + cc * 4);
    }
    __syncthreads();
  }
}

// ---------------- round-1 fallback (used only if ws is too small) ----------------
__global__ __launch_bounds__(256) void moe_head_fallback(
    const float* __restrict__ xs0, const float* __restrict__ xs1,
    const float* __restrict__ xs2, const float* __restrict__ xs3,
    const float* __restrict__ gates,
    const float* __restrict__ W0, const float* __restrict__ b0,
    const float* __restrict__ W1, const float* __restrict__ b1,
    const float* __restrict__ W2, const float* __restrict__ b2,
    const float* __restrict__ W3, const float* __restrict__ b3,
    float* __restrict__ out)
{
  __shared__ __align__(16) unsigned short a_lds[64 * 64];
  __shared__ __align__(16) unsigned short b_lds[64 * 64];
  __shared__ __align__(16) float t_lds[4][32 * 36];
  const int tid = threadIdx.x;
  const int lane = tid & 63;
  const int wid = tid >> 6;
  const int wm = wid >> 1, wn = wid & 1;
  const int nt = blockIdx.x, mt = blockIdx.y;
  const int mbase = mt * 64, nbase = nt * 64;
  const float* xarr[4] = {xs0, xs1, xs2, xs3};
  const float* Warr[4] = {W0, W1, W2, W3};
  const float* barr[4] = {b0, b1, b2, b3};
  constexpr int Larr[4] = {32, 16, 8, 4};
  f32x4 comb[2][2] = {};
#pragma unroll
  for (int e = 0; e < 4; ++e) {
    const int L = Larr[e];
    const float* xlast = xarr[e] + (size_t)(L - 1) * 1024;
    const size_t xstride = (size_t)L * 1024;
    const float* Wp = Warr[e];
    f32x4 acc[2][2] = {};
    for (int kt = 0; kt < 16; ++kt) {
      const int k0 = kt * 64;
      __syncthreads();
      {
        const int k_l = (tid & 15) * 4;
        const int r0 = tid >> 4;
#pragma unroll
        for (int j = 0; j < 4; ++j) {
          const int row = r0 + j * 16;
          f32x4 v = *(const f32x4*)(xlast + (size_t)(mbase + row) * xstride + (k0 + k_l));
          u16x4 pk;
          pk[0] = f2bf(v[0]); pk[1] = f2bf(v[1]); pk[2] = f2bf(v[2]); pk[3] = f2bf(v[3]);
          const int byte = (row * 128 + k_l * 2) ^ ((row & 7) << 4);
          *(u16x4*)((char*)a_lds + byte) = pk;
        }
      }
      {
        const int n_l = tid & 63;
        const int kq = tid >> 6;
        const int n_g = nbase + n_l;
        const bool nok = (n_g < 720);
        const float* wcol = Wp + n_g;
#pragma unroll
        for (int g = 0; g < 4; ++g) {
          const int k_l = kq * 4 + g * 16;
          float w0 = 0.f, w1 = 0.f, w2 = 0.f, w3 = 0.f;
          if (nok) {
            const float* s = wcol + (size_t)(k0 + k_l) * 720;
            w0 = s[0]; w1 = s[720]; w2 = s[1440]; w3 = s[2160];
          }
          u16x4 pk;
          pk[0] = f2bf(w0); pk[1] = f2bf(w1); pk[2] = f2bf(w2); pk[3] = f2bf(w3);
          const int byte = (n_l * 128 + k_l * 2) ^ ((n_l & 7) << 4);
          *(u16x4*)((char*)b_lds + byte) = pk;
        }
      }
      __syncthreads();
#pragma unroll
      for (int ks = 0; ks < 2; ++ks) {
        const int kb2 = (ks * 32 + (lane >> 4) * 8) * 2;
        bf16x8 af[2], bfr[2];
#pragma unroll
        for (int mf = 0; mf < 2; ++mf) {
          const int r = wm * 32 + mf * 16 + (lane & 15);
          const int byte = (r * 128 + kb2) ^ ((r & 7) << 4);
          af[mf] = *(const bf16x8*)((const char*)a_lds + byte);
        }
#pragma unroll
        for (int nf = 0; nf < 2; ++nf) {
          const int r = wn * 32 + nf * 16 + (lane & 15);
          const int byte = (r * 128 + kb2) ^ ((r & 7) << 4);
          bfr[nf] = *(const bf16x8*)((const char*)b_lds + byte);
        }
#pragma unroll
        for (int mf = 0; mf < 2; ++mf)
#pragma unroll
          for (int nf = 0; nf < 2; ++nf)
            acc[mf][nf] = __builtin_amdgcn_mfma_f32_16x16x32_bf16(
                af[mf], bfr[nf], acc[mf][nf], 0, 0, 0);
      }
    }
    {
      const int b_idx = mt * 2 + wm;
      const float g = gates[b_idx * 4 + e];
#pragma unroll
      for (int nf = 0; nf < 2; ++nf) {
        const int col = nbase + wn * 32 + nf * 16 + (lane & 15);
        const float bias = (col < 720) ? barr[e][col] : 0.0f;
#pragma unroll
        for (int mf = 0; mf < 2; ++mf)
#pragma unroll
          for (int j = 0; j < 4; ++j)
            comb[mf][nf][j] += g * __expf(acc[mf][nf][j] + bias);
      }
    }
  }
  {
    float* tl = &t_lds[wid][0];
#pragma unroll
    for (int mf = 0; mf < 2; ++mf)
#pragma unroll
      for (int nf = 0; nf < 2; ++nf)
#pragma unroll
        for (int j = 0; j < 4; ++j) {
          const int row_l = mf * 16 + (lane >> 4) * 4 + j;
          const int col_l = nf * 16 + (lane & 15);
          float v = comb[mf][nf][j];
          v = (v == 0.0f) ? EPSV : v;
          tl[col_l * 36 + row_l] = __logf(v);
        }
    __syncthreads();
    const int b_idx = mt * 2 + wm;
    const int pbase = nbase + wn * 32;
#pragma unroll
    for (int it = 0; it < 4; ++it) {
      const int p_l = it * 8 + (lane >> 3);
      const int p = pbase + p_l;
      if (p < 720) {
        f32x4 v = *(const f32x4*)(tl + p_l * 36 + (lane & 7) * 4);
        *(f32x4*)(out + ((size_t)b_idx * 720 + p) * 32 + (lane & 7) * 4) = v;
      }
    }
  }
}

extern "C" void kernel_launch(void* const* d_in, const int* in_sizes, int n_in,
                              void* d_out, int out_size, void* d_ws, size_t ws_size,
                              hipStream_t stream) {
  const size_t xb_elems = (size_t)4 * 2048 * 1024;
  const size_t wb_elems = (size_t)4 * 720 * 1024;
  const size_t plane_elems = (size_t)4 * 2048 * 720;
  const size_t need = (xb_elems + wb_elems + plane_elems) * 2 + 512;
  if (ws_size >= need) {
    unsigned short* Xb = (unsigned short*)d_ws;
    unsigned short* Wb = Xb + xb_elems;
    unsigned short* planes = Wb + wb_elems;
    unsigned int* ctr = (unsigned int*)(planes + plane_elems);
    prep_fused<<<4096 + 768, 256, 0, stream>>>(
        (const float*)d_in[0], (const float*)d_in[1],
        (const float*)d_in[2], (const float*)d_in[3],
        (const float*)d_in[5], (const float*)d_in[7],
        (const float*)d_in[9], (const float*)d_in[11],
        Xb, Wb, ctr);
    moe_gemm_e<<<384, 512, 0, stream>>>(
        Xb, Wb, (const float*)d_in[4],
        (const float*)d_in[6], (const float*)d_in[8],
        (const float*)d_in[10], (const float*)d_in[12],
        planes, ctr, (float*)d_out);
  } else {
    moe_head_fallback<<<dim3(12, 32), 256, 0, stream>>>(
        (const float*)d_in[0], (const float*)d_in[1],
        (const float*)d_in[2], (const float*)d_in[3],
        (const float*)d_in[4],
        (const float*)d_in[5], (const float*)d_in[6],
        (const float*)d_in[7], (const float*)d_in[8],
        (const float*)d_in[9], (const float*)d_in[10],
        (const float*)d_in[11], (const float*)d_in[12],
        (float*)d_out);
  }
}

// Round 12
// 39.207 us; speedup vs baseline: 4.8561x; 4.8561x over previous
//
#include <hip/hip_runtime.h>
#include <hip/hip_bf16.h>

// LinearPredictionHead: 4-expert last-token linear heads + dense-gate log-sum-exp combine.
// out[b,p,c] = log( sum_e gates[b,e] * exp( dot(xs_e[b,c,-1,:], W_e[:,p]) + b_e[p] ) )
// Round 12: R6 (best, 38.7us) with ONE change: the GEMM plane-write epilogue is
// re-staged through LDS (free after the K-loop) so planes are written with
// coalesced u16x8 vector stores instead of 16 stride-1440B scalar u16 stores
// per thread. Everything else byte-identical to validated R6.
// (R11 lesson: cross-XCD fences/atomics cost >100us -> no fusion via coherence.)

typedef __attribute__((ext_vector_type(4))) float f32x4;
typedef __attribute__((ext_vector_type(8))) short bf16x8;
typedef __attribute__((ext_vector_type(4))) unsigned short u16x4;
typedef __attribute__((ext_vector_type(8))) unsigned short u16x8;

#define EPSV 2.2204460492503131e-16f

__device__ __forceinline__ unsigned short f2bf(float f) {
  unsigned u = __builtin_bit_cast(unsigned, f);
  u += 0x7fffu + ((u >> 16) & 1u);   // round-to-nearest-even
  return (unsigned short)(u >> 16);
}
__device__ __forceinline__ float bf2f(unsigned short h) {
  unsigned u = ((unsigned)h) << 16;
  return __builtin_bit_cast(float, u);
}
__device__ __forceinline__ void gload_lds16(const void* g, void* l) {
  __builtin_amdgcn_global_load_lds(
      (const __attribute__((address_space(1))) unsigned int*)g,
      (__attribute__((address_space(3))) unsigned int*)l, 16, 0, 0);
}

// ---------------- prep (fused): X last tokens -> bf16 [4][2048][1024]
//                               + W [1024][720] -> bf16 W^T [4][720][1024] ----
__global__ __launch_bounds__(256) void prep_fused(
    const float* __restrict__ xs0, const float* __restrict__ xs1,
    const float* __restrict__ xs2, const float* __restrict__ xs3,
    const float* __restrict__ W0, const float* __restrict__ W1,
    const float* __restrict__ W2, const float* __restrict__ W3,
    unsigned short* __restrict__ Xb, unsigned short* __restrict__ Wb)
{
  __shared__ __align__(16) unsigned short tile[64 * 72];  // W path only
  const int tid = threadIdx.x;
  if (blockIdx.x < 4096) {
    // ---- X path (validated) ----
    const int i = blockIdx.x * 256 + tid;          // 8 elems each
    const int e = i >> 18;
    const int rem = i & 262143;
    const int m = rem >> 7;
    const int kc = rem & 127;
    const float* xp = (e == 0) ? xs0 : (e == 1) ? xs1 : (e == 2) ? xs2 : xs3;
    const int L = 32 >> e;                         // 32,16,8,4
    const float* src = xp + ((size_t)m * L + (L - 1)) * 1024 + kc * 8;
    f32x4 v0 = *(const f32x4*)src;
    f32x4 v1 = *(const f32x4*)(src + 4);
    u16x8 pk;
    pk[0] = f2bf(v0[0]); pk[1] = f2bf(v0[1]); pk[2] = f2bf(v0[2]); pk[3] = f2bf(v0[3]);
    pk[4] = f2bf(v1[0]); pk[5] = f2bf(v1[1]); pk[6] = f2bf(v1[2]); pk[7] = f2bf(v1[3]);
    *(u16x8*)(Xb + ((size_t)e * 2048 + m) * 1024 + kc * 8) = pk;
  } else {
    // ---- W path (validated) ----
    const int wI = blockIdx.x - 4096;              // 0..767 = 16 k x 12 n x 4 e
    const int k0 = (wI & 15) * 64;
    const int rest = wI >> 4;
    const int nb = (rest % 12) * 64;
    const int e = rest / 12;
    const float* Wp = (e == 0) ? W0 : (e == 1) ? W1 : (e == 2) ? W2 : W3;
    const int n_c = tid & 15;
    const int r = tid >> 4;
    const int n0 = nb + n_c * 4;
#pragma unroll
    for (int j = 0; j < 4; ++j) {
      const int row = r + j * 16;
      f32x4 v = {0.f, 0.f, 0.f, 0.f};
      if (n0 < 720) v = *(const f32x4*)(Wp + (size_t)(k0 + row) * 720 + n0);
#pragma unroll
      for (int d = 0; d < 4; ++d) tile[(n_c * 4 + d) * 72 + row] = f2bf(v[d]);
    }
    __syncthreads();
    const int n_l = tid >> 2;
    const int kq = tid & 3;
    if (nb + n_l < 720) {
#pragma unroll
      for (int q = 0; q < 2; ++q) {
        const int chunk = q * 4 + kq;
        *(u16x8*)(Wb + ((size_t)e * 720 + nb + n_l) * 1024 + k0 + chunk * 8) =
            *(const u16x8*)(tile + n_l * 72 + chunk * 8);
      }
    }
  }
}

// ---------------- GEMM per expert: planes[e][m][p] = bf16(g * exp(o_e + bias)) -
// 128x128 tile, 8 waves (2 wm x 4 wn), wave-tile 64x32, BK=64, 16 K-steps,
// dbuf LDS (64KB), single-__syncthreads 2-phase (R6, validated).
// Epilogue: g*exp staged to LDS [128][136] u16, then coalesced u16x8 stores.
// Grid 384 = 6nt*16mt*4e, XCD-chunked bijection (384 % 8 == 0).
__global__ __launch_bounds__(512) void moe_gemm_e(
    const unsigned short* __restrict__ Xb, const unsigned short* __restrict__ Wb,
    const float* __restrict__ gates,
    const float* __restrict__ b0, const float* __restrict__ b1,
    const float* __restrict__ b2, const float* __restrict__ b3,
    unsigned short* __restrict__ planes)
{
  __shared__ __align__(16) unsigned char smem[65536];
  unsigned short* a_lds = (unsigned short*)smem;            // [2][128*64] = 32KB
  unsigned short* b_lds = (unsigned short*)(smem + 32768);  // [2][128*64] = 32KB

  const int tid = threadIdx.x;
  const int lane = tid & 63;
  const int wid = tid >> 6;          // 0..7
  const int wm = wid >> 2;           // 0..1 : 64-row half
  const int wn = wid & 3;            // 0..3 : 32-col quarter

  // XCD-chunked bijection: XCD x gets contiguous ids [x*48, (x+1)*48)
  const int id = ((int)blockIdx.x & 7) * 48 + ((int)blockIdx.x >> 3);
  const int nt = id % 6;             // 6 N-tiles of 128 (last ragged: 720-640=80)
  const int mt = (id / 6) % 16;      // 16 M-tiles of 128
  const int e  = id / 96;
  const int nbase = nt * 128;

  const float* barr[4] = {b0, b1, b2, b3};
  // wave rows mt*128 + wm*64 + mf*16: batch = mt*4 + wm*2 + (mf>>1)
  float g_r[2];
#pragma unroll
  for (int h = 0; h < 2; ++h)
    g_r[h] = gates[(mt * 4 + wm * 2 + h) * 4 + e];
  float bias_r[2];
#pragma unroll
  for (int nf = 0; nf < 2; ++nf) {
    int col = nbase + wn * 32 + nf * 16 + (lane & 15);
    bias_r[nf] = barr[e][col < 720 ? col : 719];
  }

  const unsigned short* asrc = Xb + (size_t)e * 2048 * 1024 + (size_t)mt * 128 * 1024;
  const unsigned short* bsrc = Wb + (size_t)e * 720 * 1024;

  // stage: A 128x64 (1024 chunks) + B 128x64 (1024 chunks), 4 loads/thread.
  // LDS dst linear; global src pre-swizzled with the read-side XOR (m173/#21).
  auto stage = [&](int k0, int buf) {
#pragma unroll
    for (int j = 0; j < 2; ++j) {
      const int C = j * 512 + tid;
      const int row = C >> 3, c = C & 7;
      gload_lds16(asrc + (size_t)row * 1024 + k0 + ((c ^ (row & 7)) * 8),
                  a_lds + buf * 8192 + C * 8);
    }
#pragma unroll
    for (int j = 0; j < 2; ++j) {
      const int C = j * 512 + tid;
      const int row = C >> 3, c = C & 7;
      int n = nbase + row; if (n > 719) n = 719;  // clamp; stores guarded later
      gload_lds16(bsrc + (size_t)n * 1024 + k0 + ((c ^ (row & 7)) * 8),
                  b_lds + buf * 8192 + C * 8);
    }
  };

  auto compute = [&](int buf, f32x4 (&acc)[4][2]) {
    const unsigned short* al = a_lds + buf * 8192;
    const unsigned short* bl = b_lds + buf * 8192;
#pragma unroll
    for (int ks = 0; ks < 2; ++ks) {
      const int kb = ks * 64 + (lane >> 4) * 16;  // byte offset within 128B row
      bf16x8 af[4], bfm[2];
#pragma unroll
      for (int mf = 0; mf < 4; ++mf) {
        const int r = wm * 64 + mf * 16 + (lane & 15);
        const int byte = (r * 128 + kb) ^ ((r & 7) << 4);
        af[mf] = *(const bf16x8*)((const char*)al + byte);
      }
#pragma unroll
      for (int nf = 0; nf < 2; ++nf) {
        const int r = wn * 32 + nf * 16 + (lane & 15);
        const int byte = (r * 128 + kb) ^ ((r & 7) << 4);
        bfm[nf] = *(const bf16x8*)((const char*)bl + byte);
      }
#pragma unroll
      for (int mf = 0; mf < 4; ++mf)
#pragma unroll
        for (int nf = 0; nf < 2; ++nf)
          acc[mf][nf] = __builtin_amdgcn_mfma_f32_16x16x32_bf16(
              af[mf], bfm[nf], acc[mf][nf], 0, 0, 0);
    }
  };

  f32x4 acc[4][2] = {};
  int cur = 0;
  stage(0, 0);
  __syncthreads();
  for (int kt = 0; kt < 16; ++kt) {
    if (kt < 15) stage((kt + 1) * 64, cur ^ 1);  // next-tile loads fly during compute
    compute(cur, acc);
    __syncthreads();                             // drain + barrier (proven structure)
    cur ^= 1;
  }

  // ---- epilogue: v = bf16(g*exp(acc+bias)) -> LDS [128][136] -> coalesced ----
  {
    unsigned short* t = (unsigned short*)smem;   // LDS free after last sync
    // write fragments to LDS (u16 scalar, padded stride 136 breaks bank aliasing)
#pragma unroll
    for (int nf = 0; nf < 2; ++nf) {
      const int col = wn * 32 + nf * 16 + (lane & 15);    // p-local 0..127
#pragma unroll
      for (int mf = 0; mf < 4; ++mf) {
        const int row0 = wm * 64 + mf * 16 + ((lane >> 4) << 2);  // m-local
        const float g = g_r[mf >> 1];
#pragma unroll
        for (int j = 0; j < 4; ++j)
          t[(row0 + j) * 136 + col] = f2bf(g * __expf(acc[mf][nf][j] + bias_r[nf]));
      }
    }
    __syncthreads();
    // coalesced store: 2048 u16x8 chunks (128 rows x 16 p-chunks), 4 per thread.
    // ragged nt=5: p spans 640..767 but only 720 valid -> pc < 10 (80 = 10*8).
    const int pcmax = (nbase == 640) ? 10 : 16;
#pragma unroll
    for (int q = 0; q < 4; ++q) {
      const int C = q * 512 + tid;
      const int row = C >> 4;        // m-local 0..127
      const int pc = C & 15;
      if (pc < pcmax) {
        u16x8 v = *(const u16x8*)(t + row * 136 + pc * 8);
        *(u16x8*)(planes + ((size_t)e * 2048 + mt * 128 + row) * 720 + nbase + pc * 8) = v;
      }
    }
  }
}

// ---------------- reduce: sum 4 bf16 planes, log, transpose -> out[b][p][c] ---
__global__ __launch_bounds__(256) void reduce_log(
    const unsigned short* __restrict__ planes, float* __restrict__ out)
{
  __shared__ __align__(16) float t[64 * 36];
  const int nt = blockIdx.x;         // 12 p-tiles of 64
  const int b  = blockIdx.y;         // 64 batches (32 c-rows each)
  const int nbase = nt * 64;
  const int tid = threadIdx.x;

  // phase 1: 32 c-rows x 8 p-chunks (u16x8) = 256 chunks, one per thread
  {
    const int row = tid >> 3;        // c 0..31
    const int pc = tid & 7;
    int p0 = nbase + pc * 8;
    if (p0 > 712) p0 = 712;          // clamp (t entries for p>=720 never stored)
    const size_t base = ((size_t)b * 32 + row) * 720 + p0;
    float s[8] = {};
#pragma unroll
    for (int pl = 0; pl < 4; ++pl) {
      u16x8 v = *(const u16x8*)(planes + (size_t)pl * 2048 * 720 + base);
#pragma unroll
      for (int d = 0; d < 8; ++d) s[d] += bf2f(v[d]);
    }
    const int pbase_l = (p0 - nbase);
#pragma unroll
    for (int d = 0; d < 8; ++d) {
      float v = s[d];
      v = (v == 0.0f) ? EPSV : v;
      t[(pbase_l + d) * 36 + row] = __logf(v);
    }
  }
  __syncthreads();
  // phase 2: 64 p x 8 c-chunks = 512 f32x4, two per thread
#pragma unroll
  for (int it = 0; it < 2; ++it) {
    const int i = it * 256 + tid;
    const int p_l = i >> 3;
    const int cc = i & 7;
    const int p = nbase + p_l;
    if (p < 720) {
      f32x4 v = *(const f32x4*)(t + p_l * 36 + cc * 4);
      *(f32x4*)(out + ((size_t)b * 720 + p) * 32 + cc * 4) = v;
    }
  }
}

// ---------------- round-1 fallback (used only if ws is too small) ----------------
__global__ __launch_bounds__(256) void moe_head_fallback(
    const float* __restrict__ xs0, const float* __restrict__ xs1,
    const float* __restrict__ xs2, const float* __restrict__ xs3,
    const float* __restrict__ gates,
    const float* __restrict__ W0, const float* __restrict__ b0,
    const float* __restrict__ W1, const float* __restrict__ b1,
    const float* __restrict__ W2, const float* __restrict__ b2,
    const float* __restrict__ W3, const float* __restrict__ b3,
    float* __restrict__ out)
{
  __shared__ __align__(16) unsigned short a_lds[64 * 64];
  __shared__ __align__(16) unsigned short b_lds[64 * 64];
  __shared__ __align__(16) float t_lds[4][32 * 36];
  const int tid = threadIdx.x;
  const int lane = tid & 63;
  const int wid = tid >> 6;
  const int wm = wid >> 1, wn = wid & 1;
  const int nt = blockIdx.x, mt = blockIdx.y;
  const int mbase = mt * 64, nbase = nt * 64;
  const float* xarr[4] = {xs0, xs1, xs2, xs3};
  const float* Warr[4] = {W0, W1, W2, W3};
  const float* barr[4] = {b0, b1, b2, b3};
  constexpr int Larr[4] = {32, 16, 8, 4};
  f32x4 comb[2][2] = {};
#pragma unroll
  for (int e = 0; e < 4; ++e) {
    const int L = Larr[e];
    const float* xlast = xarr[e] + (size_t)(L - 1) * 1024;
    const size_t xstride = (size_t)L * 1024;
    const float* Wp = Warr[e];
    f32x4 acc[2][2] = {};
    for (int kt = 0; kt < 16; ++kt) {
      const int k0 = kt * 64;
      __syncthreads();
      {
        const int k_l = (tid & 15) * 4;
        const int r0 = tid >> 4;
#pragma unroll
        for (int j = 0; j < 4; ++j) {
          const int row = r0 + j * 16;
          f32x4 v = *(const f32x4*)(xlast + (size_t)(mbase + row) * xstride + (k0 + k_l));
          u16x4 pk;
          pk[0] = f2bf(v[0]); pk[1] = f2bf(v[1]); pk[2] = f2bf(v[2]); pk[3] = f2bf(v[3]);
          const int byte = (row * 128 + k_l * 2) ^ ((row & 7) << 4);
          *(u16x4*)((char*)a_lds + byte) = pk;
        }
      }
      {
        const int n_l = tid & 63;
        const int kq = tid >> 6;
        const int n_g = nbase + n_l;
        const bool nok = (n_g < 720);
        const float* wcol = Wp + n_g;
#pragma unroll
        for (int g = 0; g < 4; ++g) {
          const int k_l = kq * 4 + g * 16;
          float w0 = 0.f, w1 = 0.f, w2 = 0.f, w3 = 0.f;
          if (nok) {
            const float* s = wcol + (size_t)(k0 + k_l) * 720;
            w0 = s[0]; w1 = s[720]; w2 = s[1440]; w3 = s[2160];
          }
          u16x4 pk;
          pk[0] = f2bf(w0); pk[1] = f2bf(w1); pk[2] = f2bf(w2); pk[3] = f2bf(w3);
          const int byte = (n_l * 128 + k_l * 2) ^ ((n_l & 7) << 4);
          *(u16x4*)((char*)b_lds + byte) = pk;
        }
      }
      __syncthreads();
#pragma unroll
      for (int ks = 0; ks < 2; ++ks) {
        const int kb2 = (ks * 32 + (lane >> 4) * 8) * 2;
        bf16x8 af[2], bfr[2];
#pragma unroll
        for (int mf = 0; mf < 2; ++mf) {
          const int r = wm * 32 + mf * 16 + (lane & 15);
          const int byte = (r * 128 + kb2) ^ ((r & 7) << 4);
          af[mf] = *(const bf16x8*)((const char*)a_lds + byte);
        }
#pragma unroll
        for (int nf = 0; nf < 2; ++nf) {
          const int r = wn * 32 + nf * 16 + (lane & 15);
          const int byte = (r * 128 + kb2) ^ ((r & 7) << 4);
          bfr[nf] = *(const bf16x8*)((const char*)b_lds + byte);
        }
#pragma unroll
        for (int mf = 0; mf < 2; ++mf)
#pragma unroll
          for (int nf = 0; nf < 2; ++nf)
            acc[mf][nf] = __builtin_amdgcn_mfma_f32_16x16x32_bf16(
                af[mf], bfr[nf], acc[mf][nf], 0, 0, 0);
      }
    }
    {
      const int b_idx = mt * 2 + wm;
      const float g = gates[b_idx * 4 + e];
#pragma unroll
      for (int nf = 0; nf < 2; ++nf) {
        const int col = nbase + wn * 32 + nf * 16 + (lane & 15);
        const float bias = (col < 720) ? barr[e][col] : 0.0f;
#pragma unroll
        for (int mf = 0; mf < 2; ++mf)
#pragma unroll
          for (int j = 0; j < 4; ++j)
            comb[mf][nf][j] += g * __expf(acc[mf][nf][j] + bias);
      }
    }
  }
  {
    float* tl = &t_lds[wid][0];
#pragma unroll
    for (int mf = 0; mf < 2; ++mf)
#pragma unroll
      for (int nf = 0; nf < 2; ++nf)
#pragma unroll
        for (int j = 0; j < 4; ++j) {
          const int row_l = mf * 16 + (lane >> 4) * 4 + j;
          const int col_l = nf * 16 + (lane & 15);
          float v = comb[mf][nf][j];
          v = (v == 0.0f) ? EPSV : v;
          tl[col_l * 36 + row_l] = __logf(v);
        }
    __syncthreads();
    const int b_idx = mt * 2 + wm;
    const int pbase = nbase + wn * 32;
#pragma unroll
    for (int it = 0; it < 4; ++it) {
      const int p_l = it * 8 + (lane >> 3);
      const int p = pbase + p_l;
      if (p < 720) {
        f32x4 v = *(const f32x4*)(tl + p_l * 36 + (lane & 7) * 4);
        *(f32x4*)(out + ((size_t)b_idx * 720 + p) * 32 + (lane & 7) * 4) = v;
      }
    }
  }
}

extern "C" void kernel_launch(void* const* d_in, const int* in_sizes, int n_in,
                              void* d_out, int out_size, void* d_ws, size_t ws_size,
                              hipStream_t stream) {
  const size_t xb_elems = (size_t)4 * 2048 * 1024;
  const size_t wb_elems = (size_t)4 * 720 * 1024;
  const size_t plane_elems = (size_t)4 * 2048 * 720;
  const size_t need = (xb_elems + wb_elems + plane_elems) * 2;
  if (ws_size >= need) {
    unsigned short* Xb = (unsigned short*)d_ws;
    unsigned short* Wb = Xb + xb_elems;
    unsigned short* planes = Wb + wb_elems;
    prep_fused<<<4096 + 768, 256, 0, stream>>>(
        (const float*)d_in[0], (const float*)d_in[1],
        (const float*)d_in[2], (const float*)d_in[3],
        (const float*)d_in[5], (const float*)d_in[7],
        (const float*)d_in[9], (const float*)d_in[11],
        Xb, Wb);
    moe_gemm_e<<<384, 512, 0, stream>>>(
        Xb, Wb, (const float*)d_in[4],
        (const float*)d_in[6], (const float*)d_in[8],
        (const float*)d_in[10], (const float*)d_in[12],
        planes);
    reduce_log<<<dim3(12, 64), 256, 0, stream>>>(planes, (float*)d_out);
  } else {
    moe_head_fallback<<<dim3(12, 32), 256, 0, stream>>>(
        (const float*)d_in[0], (const float*)d_in[1],
        (const float*)d_in[2], (const float*)d_in[3],
        (const float*)d_in[4],
        (const float*)d_in[5], (const float*)d_in[6],
        (const float*)d_in[7], (const float*)d_in[8],
        (const float*)d_in[9], (const float*)d_in[10],
        (const float*)d_in[11], (const float*)d_in[12],
        (float*)d_out);
  }
}